// Round 1
// baseline (22451.877 us; speedup 1.0000x reference)
//
#include <hip/hip_runtime.h>
#include <math.h>

// Problem constants
#define BB 32
#define TT 512
#define INF_ 128
#define HH 256
#define H3 768
#define NHEADS 4
#define HDIM 64

// ---------------- wave helpers (wave = 64 on CDNA) ----------------
__device__ __forceinline__ float wsum(float v) {
#pragma unroll
  for (int o = 32; o > 0; o >>= 1) v += __shfl_xor(v, o, 64);
  return v;
}
__device__ __forceinline__ float wmax(float v) {
#pragma unroll
  for (int o = 32; o > 0; o >>= 1) v = fmaxf(v, __shfl_xor(v, o, 64));
  return v;
}

// ---------------- GEMM: C[M,N] = A[M,K] * B[N,K]^T + bias ----------------
// 128x128 tile, BK=16, 256 threads, 8x8 micro-tile. Requires M%128==0,
// N%128==0, K%16==0 (true for all uses here).
__global__ __launch_bounds__(256) void gemm_bt(
    const float* __restrict__ A, const float* __restrict__ Bw,
    const float* __restrict__ bias, float* __restrict__ C,
    int M, int N, int K) {
  __shared__ __align__(16) float As[16][132];
  __shared__ __align__(16) float Bs[16][132];
  const int tid = threadIdx.x;
  const int tx = tid & 15, ty = tid >> 4;
  const int m0 = blockIdx.y * 128, n0 = blockIdx.x * 128;
  const int r = tid >> 1, kc = (tid & 1) * 8;
  float acc[8][8] = {};
  for (int k0 = 0; k0 < K; k0 += 16) {
    float4 a0 = *(const float4*)(A + (size_t)(m0 + r) * K + k0 + kc);
    float4 a1 = *(const float4*)(A + (size_t)(m0 + r) * K + k0 + kc + 4);
    float4 b0 = *(const float4*)(Bw + (size_t)(n0 + r) * K + k0 + kc);
    float4 b1 = *(const float4*)(Bw + (size_t)(n0 + r) * K + k0 + kc + 4);
    __syncthreads();  // previous tile fully consumed
    As[kc + 0][r] = a0.x; As[kc + 1][r] = a0.y; As[kc + 2][r] = a0.z; As[kc + 3][r] = a0.w;
    As[kc + 4][r] = a1.x; As[kc + 5][r] = a1.y; As[kc + 6][r] = a1.z; As[kc + 7][r] = a1.w;
    Bs[kc + 0][r] = b0.x; Bs[kc + 1][r] = b0.y; Bs[kc + 2][r] = b0.z; Bs[kc + 3][r] = b0.w;
    Bs[kc + 4][r] = b1.x; Bs[kc + 5][r] = b1.y; Bs[kc + 6][r] = b1.z; Bs[kc + 7][r] = b1.w;
    __syncthreads();
#pragma unroll
    for (int kk = 0; kk < 16; ++kk) {
      float4 x0 = *(const float4*)&As[kk][ty * 8];
      float4 x1 = *(const float4*)&As[kk][ty * 8 + 4];
      float4 y0 = *(const float4*)&Bs[kk][tx * 8];
      float4 y1 = *(const float4*)&Bs[kk][tx * 8 + 4];
      float xa[8] = {x0.x, x0.y, x0.z, x0.w, x1.x, x1.y, x1.z, x1.w};
      float yb[8] = {y0.x, y0.y, y0.z, y0.w, y1.x, y1.y, y1.z, y1.w};
#pragma unroll
      for (int i = 0; i < 8; ++i)
#pragma unroll
        for (int j = 0; j < 8; ++j) acc[i][j] += xa[i] * yb[j];
    }
  }
  float bv[8];
#pragma unroll
  for (int j = 0; j < 8; ++j) bv[j] = bias ? bias[n0 + tx * 8 + j] : 0.f;
#pragma unroll
  for (int i = 0; i < 8; ++i) {
    float4 o0 = {acc[i][0] + bv[0], acc[i][1] + bv[1], acc[i][2] + bv[2], acc[i][3] + bv[3]};
    float4 o1 = {acc[i][4] + bv[4], acc[i][5] + bv[5], acc[i][6] + bv[6], acc[i][7] + bv[7]};
    float* cp = C + (size_t)(m0 + ty * 8 + i) * N + n0 + tx * 8;
    *(float4*)cp = o0;
    *(float4*)(cp + 4) = o1;
  }
}

// ---------------- GRU recurrence: one block per batch ----------------
// xp[b,t,3H] already has x@W_ih^T + b_ih. Thread j owns hidden unit j and
// reads W_hh rows {j, H+j, 2H+j} (float4, row-major) each step. h double-
// buffered in LDS -> one barrier per step. 3 separate gate loops keep the
// per-wave L1 working set at 16KB (one 64B line per lane).
__global__ __launch_bounds__(256) void gru_layer(
    const float* __restrict__ xp, const float* __restrict__ Whh,
    const float* __restrict__ bhh, float* __restrict__ out) {
  __shared__ __align__(16) float h[2][HH];
  const int j = threadIdx.x;
  const int b = blockIdx.x;
  const float br = bhh[j], bz = bhh[HH + j], bn = bhh[2 * HH + j];
  const float* __restrict__ wr = Whh + (size_t)j * HH;
  const float* __restrict__ wz = Whh + (size_t)(HH + j) * HH;
  const float* __restrict__ wn = Whh + (size_t)(2 * HH + j) * HH;
  h[0][j] = 0.f;
  __syncthreads();
  int cur = 0;
  const float* xrow = xp + (size_t)b * TT * H3;
  float* orow = out + (size_t)b * TT * HH;
  for (int t = 0; t < TT; ++t) {
    const float* hc = h[cur];
    float ar = 0.f, az = 0.f, an = 0.f;
#pragma unroll 4
    for (int k = 0; k < HH; k += 4) {
      float4 hv = *(const float4*)(hc + k);
      float4 w4 = *(const float4*)(wr + k);
      ar += hv.x * w4.x + hv.y * w4.y + hv.z * w4.z + hv.w * w4.w;
    }
#pragma unroll 4
    for (int k = 0; k < HH; k += 4) {
      float4 hv = *(const float4*)(hc + k);
      float4 w4 = *(const float4*)(wz + k);
      az += hv.x * w4.x + hv.y * w4.y + hv.z * w4.z + hv.w * w4.w;
    }
#pragma unroll 4
    for (int k = 0; k < HH; k += 4) {
      float4 hv = *(const float4*)(hc + k);
      float4 w4 = *(const float4*)(wn + k);
      an += hv.x * w4.x + hv.y * w4.y + hv.z * w4.z + hv.w * w4.w;
    }
    float rg = 1.f / (1.f + __expf(-(xrow[j] + ar + br)));
    float zg = 1.f / (1.f + __expf(-(xrow[HH + j] + az + bz)));
    float ng = tanhf(xrow[2 * HH + j] + rg * (an + bn));
    float hnew = (1.f - zg) * ng + zg * hc[j];
    h[cur ^ 1][j] = hnew;
    orow[j] = hnew;
    __syncthreads();
    cur ^= 1;
    xrow += H3;
    orow += HH;
  }
}

// ---------------- gat_W transpose: [4,256,64] -> [256 cols][256 k] ----------------
__global__ void gat_wt(const float* __restrict__ W, float* __restrict__ Wt) {
  int idx = blockIdx.x * 256 + threadIdx.x;  // [0, 65536)
  int col = idx >> 8, k = idx & 255;
  Wt[idx] = W[((size_t)((col >> 6) * HH + k)) * HDIM + (col & 63)];
}

// ---------------- GAT f_src/f_dst ----------------
__global__ void gat_fsd(const float* __restrict__ hgat, const float* __restrict__ a,
                        float* __restrict__ fsrc, float* __restrict__ fdst) {
  int b = blockIdx.x, hd = blockIdx.y, t = threadIdx.x;  // block 512
  const float* hp = hgat + ((size_t)(b * TT + t)) * HH + hd * HDIM;
  const float* ap = a + hd * 2 * HDIM;
  float fs = 0.f, fd = 0.f;
#pragma unroll 4
  for (int d = 0; d < HDIM; ++d) {
    float hv = hp[d];
    fs += hv * ap[d];
    fd += hv * ap[HDIM + d];
  }
  fsrc[(b * NHEADS + hd) * TT + t] = fs;
  fdst[(b * NHEADS + hd) * TT + t] = fd;
}

// ---------------- GAT flash attention ----------------
// grid (T/32, 4 heads, B); block 256 = 4 waves x 8 rows. e_ij = lrelu(fi+fj),
// online softmax, acc lanes-over-d.
__global__ __launch_bounds__(256) void gat_attn(
    const float* __restrict__ hgat, const float* __restrict__ fsrc,
    const float* __restrict__ fdst, float* __restrict__ out) {
  __shared__ __align__(16) float Ht[128][64];
  __shared__ __align__(16) float fd[128];
  __shared__ __align__(16) float pq[4][128][8];
  const int tid = threadIdx.x, wave = tid >> 6, lane = tid & 63;
  const int hd = blockIdx.y, b = blockIdx.z;
  const int i0 = blockIdx.x * 32 + wave * 8;
  const float* fs = fsrc + (size_t)(b * NHEADS + hd) * TT;
  const float* fdp = fdst + (size_t)(b * NHEADS + hd) * TT;
  float m[8], l[8], acc[8], fi[8];
#pragma unroll
  for (int q = 0; q < 8; ++q) { m[q] = -1e30f; l[q] = 0.f; acc[q] = 0.f; fi[q] = fs[i0 + q]; }
  for (int jt = 0; jt < TT; jt += 128) {
#pragma unroll
    for (int u = 0; u < 8; ++u) {
      int idx = tid + u * 256;
      int jj = idx >> 4, dq = (idx & 15) * 4;
      *(float4*)&Ht[jj][dq] =
          *(const float4*)&hgat[((size_t)(b * TT + jt + jj)) * HH + hd * HDIM + dq];
    }
    if (tid < 128) fd[tid] = fdp[jt + tid];
    __syncthreads();
#pragma unroll
    for (int q = 0; q < 8; ++q) {
      float e0 = fi[q] + fd[lane];      e0 = (e0 > 0.f) ? e0 : 0.2f * e0;
      float e1 = fi[q] + fd[lane + 64]; e1 = (e1 > 0.f) ? e1 : 0.2f * e1;
      float mn = fmaxf(m[q], wmax(fmaxf(e0, e1)));
      float corr = __expf(m[q] - mn);
      float p0 = __expf(e0 - mn), p1 = __expf(e1 - mn);
      l[q] = l[q] * corr + wsum(p0 + p1);
      m[q] = mn;
      acc[q] *= corr;
      pq[wave][lane][q] = p0;
      pq[wave][lane + 64][q] = p1;
    }
#pragma unroll 4
    for (int jj = 0; jj < 128; ++jj) {
      float4 pa = *(const float4*)&pq[wave][jj][0];
      float4 pb = *(const float4*)&pq[wave][jj][4];
      float hv = Ht[jj][lane];
      acc[0] += pa.x * hv; acc[1] += pa.y * hv; acc[2] += pa.z * hv; acc[3] += pa.w * hv;
      acc[4] += pb.x * hv; acc[5] += pb.y * hv; acc[6] += pb.z * hv; acc[7] += pb.w * hv;
    }
    __syncthreads();
  }
#pragma unroll
  for (int q = 0; q < 8; ++q)
    out[((size_t)(b * TT + i0 + q)) * HH + hd * HDIM + lane] = acc[q] / l[q];
}

// ---------------- residual + LayerNorm ----------------
__global__ __launch_bounds__(256) void ln_res(
    const float* __restrict__ g, const float* __restrict__ gat,
    const float* __restrict__ gamma, const float* __restrict__ beta,
    float* __restrict__ y) {
  int wave = threadIdx.x >> 6, lane = threadIdx.x & 63;
  size_t n = (size_t)blockIdx.x * 4 + wave;
  float4 v = ((const float4*)(g + n * HH))[lane];
  float4 w = ((const float4*)(gat + n * HH))[lane];
  v.x += w.x; v.y += w.y; v.z += w.z; v.w += w.w;
  float mu = wsum(v.x + v.y + v.z + v.w) * (1.f / 256.f);
  float dx = v.x - mu, dy = v.y - mu, dz = v.z - mu, dw = v.w - mu;
  float var = wsum(dx * dx + dy * dy + dz * dz + dw * dw) * (1.f / 256.f);
  float rstd = rsqrtf(var + 1e-5f);
  float4 gm = ((const float4*)gamma)[lane];
  float4 bt = ((const float4*)beta)[lane];
  float4 o = {dx * rstd * gm.x + bt.x, dy * rstd * gm.y + bt.y,
              dz * rstd * gm.z + bt.z, dw * rstd * gm.w + bt.w};
  ((float4*)(y + n * HH))[lane] = o;
}

// ---------------- MHA flash attention ----------------
// qkv[b,t,768] packed q|k|v; head hd dims hd*64..+63. K^T and V share an LDS
// buffer (staged in separate phases). scores scaled by 1/8.
__global__ __launch_bounds__(256) void mha_attn(const float* __restrict__ qkv,
                                                float* __restrict__ ctx) {
  __shared__ __align__(16) float KV[8320];        // K^T [64][130] | V [128][64]
  __shared__ __align__(16) float qq[4][64][8];
  __shared__ __align__(16) float pq[4][128][8];
  const int tid = threadIdx.x, wave = tid >> 6, lane = tid & 63;
  const int hd = blockIdx.y, b = blockIdx.z;
  const int i0 = blockIdx.x * 32 + wave * 8;
#pragma unroll
  for (int q = 0; q < 8; ++q)
    qq[wave][lane][q] = qkv[((size_t)(b * TT + i0 + q)) * H3 + hd * HDIM + lane];
  float m[8], l[8], acc[8];
#pragma unroll
  for (int q = 0; q < 8; ++q) { m[q] = -1e30f; l[q] = 0.f; acc[q] = 0.f; }
  for (int jt = 0; jt < TT; jt += 128) {
    // stage K^T: KV[dd*130 + j]
#pragma unroll
    for (int u = 0; u < 8; ++u) {
      int idx = tid + u * 256;
      int jj = idx >> 4, dq = (idx & 15) * 4;
      float4 kv = *(const float4*)&qkv[((size_t)(b * TT + jt + jj)) * H3 + HH + hd * HDIM + dq];
      KV[(dq + 0) * 130 + jj] = kv.x;
      KV[(dq + 1) * 130 + jj] = kv.y;
      KV[(dq + 2) * 130 + jj] = kv.z;
      KV[(dq + 3) * 130 + jj] = kv.w;
    }
    __syncthreads();
    float e0[8] = {}, e1[8] = {};
#pragma unroll 8
    for (int dd = 0; dd < 64; ++dd) {
      float4 qa = *(const float4*)&qq[wave][dd][0];
      float4 qb = *(const float4*)&qq[wave][dd][4];
      float k0 = KV[dd * 130 + lane], k1 = KV[dd * 130 + 64 + lane];
      e0[0] += qa.x * k0; e0[1] += qa.y * k0; e0[2] += qa.z * k0; e0[3] += qa.w * k0;
      e0[4] += qb.x * k0; e0[5] += qb.y * k0; e0[6] += qb.z * k0; e0[7] += qb.w * k0;
      e1[0] += qa.x * k1; e1[1] += qa.y * k1; e1[2] += qa.z * k1; e1[3] += qa.w * k1;
      e1[4] += qb.x * k1; e1[5] += qb.y * k1; e1[6] += qb.z * k1; e1[7] += qb.w * k1;
    }
    __syncthreads();  // done reading K^T
    // stage V over the same buffer: KV[j*64 + dd]
#pragma unroll
    for (int u = 0; u < 8; ++u) {
      int idx = tid + u * 256;
      int jj = idx >> 4, dq = (idx & 15) * 4;
      *(float4*)&KV[jj * 64 + dq] =
          *(const float4*)&qkv[((size_t)(b * TT + jt + jj)) * H3 + 2 * HH + hd * HDIM + dq];
    }
#pragma unroll
    for (int q = 0; q < 8; ++q) {
      float s0 = e0[q] * 0.125f, s1 = e1[q] * 0.125f;
      float mn = fmaxf(m[q], wmax(fmaxf(s0, s1)));
      float corr = __expf(m[q] - mn);
      float p0 = __expf(s0 - mn), p1 = __expf(s1 - mn);
      l[q] = l[q] * corr + wsum(p0 + p1);
      m[q] = mn;
      acc[q] *= corr;
      pq[wave][lane][q] = p0;
      pq[wave][lane + 64][q] = p1;
    }
    __syncthreads();  // V staged, pq written
#pragma unroll 4
    for (int jj = 0; jj < 128; ++jj) {
      float4 pa = *(const float4*)&pq[wave][jj][0];
      float4 pb = *(const float4*)&pq[wave][jj][4];
      float hv = KV[jj * 64 + lane];
      acc[0] += pa.x * hv; acc[1] += pa.y * hv; acc[2] += pa.z * hv; acc[3] += pa.w * hv;
      acc[4] += pb.x * hv; acc[5] += pb.y * hv; acc[6] += pb.z * hv; acc[7] += pb.w * hv;
    }
    __syncthreads();  // before next K^T overwrite
  }
#pragma unroll
  for (int q = 0; q < 8; ++q)
    ctx[((size_t)(b * TT + i0 + q)) * HH + hd * HDIM + lane] = acc[q] / l[q];
}

// ---------------- mean pool over T ----------------
__global__ void mean_pool(const float* __restrict__ x, float* __restrict__ out) {
  int b = blockIdx.x, j = threadIdx.x;
  const float* p = x + (size_t)b * TT * HH + j;
  float s = 0.f;
  for (int t = 0; t < TT; ++t) s += p[(size_t)t * HH];
  out[b * HH + j] = s * (1.f / 512.f);
}

// ---------------- FC layers ----------------
__global__ void fc1_k(const float* __restrict__ pooled, const float* __restrict__ w,
                      const float* __restrict__ bias, float* __restrict__ hid) {
  int b = blockIdx.x, o = threadIdx.x;  // 128 threads
  const float* pp = pooled + b * HH;
  const float* wp = w + o * HH;
  float s = 0.f;
#pragma unroll 4
  for (int k = 0; k < HH; ++k) s += pp[k] * wp[k];
  hid[b * 128 + o] = fmaxf(s + bias[o], 0.f);
}

__global__ void fc2_k(const float* __restrict__ hid, const float* __restrict__ w,
                      const float* __restrict__ bias, float* __restrict__ out) {
  int t = threadIdx.x;  // 256 = 32 m x 8 c
  int mm = t >> 3, c = t & 7;
  const float* hp = hid + mm * 128;
  const float* wp = w + c * 128;
  float s = 0.f;
#pragma unroll 4
  for (int k = 0; k < 128; ++k) s += hp[k] * wp[k];
  out[mm * 8 + c] = s + bias[c];
}

extern "C" void kernel_launch(void* const* d_in, const int* in_sizes, int n_in,
                              void* d_out, int out_size, void* d_ws, size_t ws_size,
                              hipStream_t stream) {
  (void)in_sizes; (void)n_in; (void)out_size; (void)ws_size;
  const float* x    = (const float*)d_in[0];
  const float* Wih0 = (const float*)d_in[1];
  const float* Whh0 = (const float*)d_in[2];
  const float* bih0 = (const float*)d_in[3];
  const float* bhh0 = (const float*)d_in[4];
  const float* Wih1 = (const float*)d_in[5];
  const float* Whh1 = (const float*)d_in[6];
  const float* bih1 = (const float*)d_in[7];
  const float* bhh1 = (const float*)d_in[8];
  const float* gatW = (const float*)d_in[9];
  const float* gatA = (const float*)d_in[10];
  const float* lng  = (const float*)d_in[11];
  const float* lnb  = (const float*)d_in[12];
  const float* inw  = (const float*)d_in[13];
  const float* inb  = (const float*)d_in[14];
  const float* outw = (const float*)d_in[15];
  const float* outb = (const float*)d_in[16];
  const float* f1w  = (const float*)d_in[17];
  const float* f1b  = (const float*)d_in[18];
  const float* f2w  = (const float*)d_in[19];
  const float* f2b  = (const float*)d_in[20];
  float* out = (float*)d_out;
  float* ws = (float*)d_ws;

  // workspace layout (floats), total 29,569,024 floats = 118.3 MB, with reuse:
  //   XPA: xp0 -> xp1 -> qkv ; G0: gru0-out -> gat_out ; Yb: y -> attn_out ;
  //   HGAT: gat per-head feats -> mha ctx
  float* XPA   = ws;                  // 16384*768
  float* G0    = ws + 12582912;       // 16384*256
  float* G1    = G0 + 4194304;        // 16384*256
  float* Yb    = G1 + 4194304;        // 16384*256
  float* HGAT  = Yb + 4194304;        // 16384*256
  float* GATWT = HGAT + 4194304;      // 256*256
  float* FSRC  = GATWT + 65536;       // 32*4*512
  float* FDST  = FSRC + 65536;        // 32*4*512
  float* POOL  = FDST + 65536;        // 32*256
  float* HIDb  = POOL + 8192;         // 32*128

  // 1. xp0 = x @ W_ih0^T + b_ih0
  gemm_bt<<<dim3(6, 128), 256, 0, stream>>>(x, Wih0, bih0, XPA, 16384, 768, 128);
  // 2. GRU layer 0
  gru_layer<<<32, 256, 0, stream>>>(XPA, Whh0, bhh0, G0);
  // 3. xp1 = g0 @ W_ih1^T + b_ih1
  gemm_bt<<<dim3(6, 128), 256, 0, stream>>>(G0, Wih1, bih1, XPA, 16384, 768, 256);
  // 4. GRU layer 1
  gru_layer<<<32, 256, 0, stream>>>(XPA, Whh1, bhh1, G1);
  // 5. GAT weight transpose + per-head features + attention
  gat_wt<<<256, 256, 0, stream>>>(gatW, GATWT);
  gemm_bt<<<dim3(2, 128), 256, 0, stream>>>(G1, GATWT, nullptr, HGAT, 16384, 256, 256);
  gat_fsd<<<dim3(32, 4), 512, 0, stream>>>(HGAT, gatA, FSRC, FDST);
  gat_attn<<<dim3(16, 4, 32), 256, 0, stream>>>(HGAT, FSRC, FDST, G0);
  // 6. y = LN(g + gat_out)
  ln_res<<<4096, 256, 0, stream>>>(G1, G0, lng, lnb, Yb);
  // 7. MHA
  gemm_bt<<<dim3(6, 128), 256, 0, stream>>>(Yb, inw, inb, XPA, 16384, 768, 256);
  mha_attn<<<dim3(16, 4, 32), 256, 0, stream>>>(XPA, HGAT);
  gemm_bt<<<dim3(2, 128), 256, 0, stream>>>(HGAT, outw, outb, Yb, 16384, 256, 256);
  // 8. pool + FC head
  mean_pool<<<32, 256, 0, stream>>>(Yb, POOL);
  fc1_k<<<32, 128, 0, stream>>>(POOL, f1w, f1b, HIDb);
  fc2_k<<<1, 256, 0, stream>>>(HIDb, f2w, f2b, out);
}

// Round 2
// 11499.011 us; speedup vs baseline: 1.9525x; 1.9525x over previous
//
#include <hip/hip_runtime.h>
#include <math.h>

// Problem constants
#define BB 32
#define TT 512
#define INF_ 128
#define HH 256
#define H3 768
#define NHEADS 4
#define HDIM 64

// ---------------- wave helpers (wave = 64 on CDNA) ----------------
__device__ __forceinline__ float wsum(float v) {
#pragma unroll
  for (int o = 32; o > 0; o >>= 1) v += __shfl_xor(v, o, 64);
  return v;
}
__device__ __forceinline__ float wmax(float v) {
#pragma unroll
  for (int o = 32; o > 0; o >>= 1) v = fmaxf(v, __shfl_xor(v, o, 64));
  return v;
}

// ---------------- GEMM: C[M,N] = A[M,K] * B[N,K]^T + bias ----------------
// 128x128 tile, BK=16, 256 threads, 8x8 micro-tile. Requires M%128==0,
// N%128==0, K%16==0 (true for all uses here).
__global__ __launch_bounds__(256) void gemm_bt(
    const float* __restrict__ A, const float* __restrict__ Bw,
    const float* __restrict__ bias, float* __restrict__ C,
    int M, int N, int K) {
  __shared__ __align__(16) float As[16][132];
  __shared__ __align__(16) float Bs[16][132];
  const int tid = threadIdx.x;
  const int tx = tid & 15, ty = tid >> 4;
  const int m0 = blockIdx.y * 128, n0 = blockIdx.x * 128;
  const int r = tid >> 1, kc = (tid & 1) * 8;
  float acc[8][8] = {};
  for (int k0 = 0; k0 < K; k0 += 16) {
    float4 a0 = *(const float4*)(A + (size_t)(m0 + r) * K + k0 + kc);
    float4 a1 = *(const float4*)(A + (size_t)(m0 + r) * K + k0 + kc + 4);
    float4 b0 = *(const float4*)(Bw + (size_t)(n0 + r) * K + k0 + kc);
    float4 b1 = *(const float4*)(Bw + (size_t)(n0 + r) * K + k0 + kc + 4);
    __syncthreads();  // previous tile fully consumed
    As[kc + 0][r] = a0.x; As[kc + 1][r] = a0.y; As[kc + 2][r] = a0.z; As[kc + 3][r] = a0.w;
    As[kc + 4][r] = a1.x; As[kc + 5][r] = a1.y; As[kc + 6][r] = a1.z; As[kc + 7][r] = a1.w;
    Bs[kc + 0][r] = b0.x; Bs[kc + 1][r] = b0.y; Bs[kc + 2][r] = b0.z; Bs[kc + 3][r] = b0.w;
    Bs[kc + 4][r] = b1.x; Bs[kc + 5][r] = b1.y; Bs[kc + 6][r] = b1.z; Bs[kc + 7][r] = b1.w;
    __syncthreads();
#pragma unroll
    for (int kk = 0; kk < 16; ++kk) {
      float4 x0 = *(const float4*)&As[kk][ty * 8];
      float4 x1 = *(const float4*)&As[kk][ty * 8 + 4];
      float4 y0 = *(const float4*)&Bs[kk][tx * 8];
      float4 y1 = *(const float4*)&Bs[kk][tx * 8 + 4];
      float xa[8] = {x0.x, x0.y, x0.z, x0.w, x1.x, x1.y, x1.z, x1.w};
      float yb[8] = {y0.x, y0.y, y0.z, y0.w, y1.x, y1.y, y1.z, y1.w};
#pragma unroll
      for (int i = 0; i < 8; ++i)
#pragma unroll
        for (int j = 0; j < 8; ++j) acc[i][j] += xa[i] * yb[j];
    }
  }
  float bv[8];
#pragma unroll
  for (int j = 0; j < 8; ++j) bv[j] = bias ? bias[n0 + tx * 8 + j] : 0.f;
#pragma unroll
  for (int i = 0; i < 8; ++i) {
    float4 o0 = {acc[i][0] + bv[0], acc[i][1] + bv[1], acc[i][2] + bv[2], acc[i][3] + bv[3]};
    float4 o1 = {acc[i][4] + bv[4], acc[i][5] + bv[5], acc[i][6] + bv[6], acc[i][7] + bv[7]};
    float* cp = C + (size_t)(m0 + ty * 8 + i) * N + n0 + tx * 8;
    *(float4*)cp = o0;
    *(float4*)(cp + 4) = o1;
  }
}

// ---------------- GRU recurrence: register-resident W_hh ----------------
// One block (1024 thr = 16 waves) per batch. Thread (j,kq), tid = kq + 4*j:
// holds W_hh rows {j, 256+j, 512+j} cols [64*kq, 64*kq+64) in 192 VGPRs,
// loaded ONCE (the old version re-read 3KB/thread/step from L2 -> 1.25%
// VALUBusy). Per step: h-slice from LDS (padded 68-stride: kq slices land on
// disjoint bank quads -> conflict-free broadcast), 192 FMAs, partial-sum
// reduce over kq via __shfl_xor(1|2) (kq lanes are adjacent in-wave), gates,
// double-buffered h write -> ONE barrier/step. h_prev for the z-blend lives
// in a register (all 4 kq lanes carry it redundantly).
__global__ __launch_bounds__(1024, 4) void gru_layer(
    const float* __restrict__ xp, const float* __restrict__ Whh,
    const float* __restrict__ bhh, float* __restrict__ out) {
  __shared__ float hs[2][4][68];
  const int tid = threadIdx.x;
  const int kq = tid & 3, j = tid >> 2;
  const int b = blockIdx.x;
  float wr[64], wz[64], wn[64];
  {
    const float* b0 = Whh + (size_t)j * HH + kq * 64;
#pragma unroll
    for (int i = 0; i < 16; ++i) {
      float4 v = *(const float4*)(b0 + i * 4);
      wr[4 * i] = v.x; wr[4 * i + 1] = v.y; wr[4 * i + 2] = v.z; wr[4 * i + 3] = v.w;
    }
#pragma unroll
    for (int i = 0; i < 16; ++i) {
      float4 v = *(const float4*)(b0 + HH * HH + i * 4);
      wz[4 * i] = v.x; wz[4 * i + 1] = v.y; wz[4 * i + 2] = v.z; wz[4 * i + 3] = v.w;
    }
#pragma unroll
    for (int i = 0; i < 16; ++i) {
      float4 v = *(const float4*)(b0 + 2 * HH * HH + i * 4);
      wn[4 * i] = v.x; wn[4 * i + 1] = v.y; wn[4 * i + 2] = v.z; wn[4 * i + 3] = v.w;
    }
  }
  const float br = bhh[j], bz = bhh[HH + j], bn = bhh[2 * HH + j];
  for (int i = tid; i < 2 * 4 * 68; i += 1024) ((float*)hs)[i] = 0.f;
  __syncthreads();
  float hprev = 0.f;
  const float* xrow = xp + (size_t)b * TT * H3;
  float* orow = out + (size_t)b * TT * HH;
  float xr = xrow[j], xz = xrow[HH + j], xn = xrow[2 * HH + j];
  for (int t = 0; t < TT; ++t) {
    float nxr = 0.f, nxz = 0.f, nxn = 0.f;
    if (t + 1 < TT) {  // prefetch next step's xp (independent of h)
      const float* x2 = xrow + H3;
      nxr = x2[j]; nxz = x2[HH + j]; nxn = x2[2 * HH + j];
    }
    const float4* hp = (const float4*)hs[t & 1][kq];
    float ar = 0.f, az = 0.f, an = 0.f;
#pragma unroll
    for (int i = 0; i < 16; ++i) {
      float4 hv = hp[i];
      ar = fmaf(hv.x, wr[4 * i], ar);
      ar = fmaf(hv.y, wr[4 * i + 1], ar);
      ar = fmaf(hv.z, wr[4 * i + 2], ar);
      ar = fmaf(hv.w, wr[4 * i + 3], ar);
      az = fmaf(hv.x, wz[4 * i], az);
      az = fmaf(hv.y, wz[4 * i + 1], az);
      az = fmaf(hv.z, wz[4 * i + 2], az);
      az = fmaf(hv.w, wz[4 * i + 3], az);
      an = fmaf(hv.x, wn[4 * i], an);
      an = fmaf(hv.y, wn[4 * i + 1], an);
      an = fmaf(hv.z, wn[4 * i + 2], an);
      an = fmaf(hv.w, wn[4 * i + 3], an);
    }
    ar += __shfl_xor(ar, 1); ar += __shfl_xor(ar, 2);
    az += __shfl_xor(az, 1); az += __shfl_xor(az, 2);
    an += __shfl_xor(an, 1); an += __shfl_xor(an, 2);
    float rg = 1.f / (1.f + __expf(-(xr + ar + br)));
    float zg = 1.f / (1.f + __expf(-(xz + az + bz)));
    float ng = 2.f / (1.f + __expf(-2.f * (xn + rg * (an + bn)))) - 1.f;  // tanh, inf-safe
    float hnew = (1.f - zg) * ng + zg * hprev;
    hprev = hnew;
    if (kq == 0) {
      hs[(t + 1) & 1][j >> 6][j & 63] = hnew;
      orow[j] = hnew;
    }
    __syncthreads();
    xr = nxr; xz = nxz; xn = nxn;
    xrow += H3; orow += HH;
  }
}

// ---------------- gat_W transpose: [4,256,64] -> [256 cols][256 k] ----------------
__global__ void gat_wt(const float* __restrict__ W, float* __restrict__ Wt) {
  int idx = blockIdx.x * 256 + threadIdx.x;  // [0, 65536)
  int col = idx >> 8, k = idx & 255;
  Wt[idx] = W[((size_t)((col >> 6) * HH + k)) * HDIM + (col & 63)];
}

// ---------------- GAT f_src/f_dst ----------------
__global__ void gat_fsd(const float* __restrict__ hgat, const float* __restrict__ a,
                        float* __restrict__ fsrc, float* __restrict__ fdst) {
  int b = blockIdx.x, hd = blockIdx.y, t = threadIdx.x;  // block 512
  const float* hp = hgat + ((size_t)(b * TT + t)) * HH + hd * HDIM;
  const float* ap = a + hd * 2 * HDIM;
  float fs = 0.f, fd = 0.f;
#pragma unroll 4
  for (int d = 0; d < HDIM; ++d) {
    float hv = hp[d];
    fs += hv * ap[d];
    fd += hv * ap[HDIM + d];
  }
  fsrc[(b * NHEADS + hd) * TT + t] = fs;
  fdst[(b * NHEADS + hd) * TT + t] = fd;
}

// ---------------- GAT flash attention ----------------
// grid (T/32, 4 heads, B); block 256 = 4 waves x 8 rows. e_ij = lrelu(fi+fj),
// online softmax, acc lanes-over-d.
__global__ __launch_bounds__(256) void gat_attn(
    const float* __restrict__ hgat, const float* __restrict__ fsrc,
    const float* __restrict__ fdst, float* __restrict__ out) {
  __shared__ __align__(16) float Ht[128][64];
  __shared__ __align__(16) float fd[128];
  __shared__ __align__(16) float pq[4][128][8];
  const int tid = threadIdx.x, wave = tid >> 6, lane = tid & 63;
  const int hd = blockIdx.y, b = blockIdx.z;
  const int i0 = blockIdx.x * 32 + wave * 8;
  const float* fs = fsrc + (size_t)(b * NHEADS + hd) * TT;
  const float* fdp = fdst + (size_t)(b * NHEADS + hd) * TT;
  float m[8], l[8], acc[8], fi[8];
#pragma unroll
  for (int q = 0; q < 8; ++q) { m[q] = -1e30f; l[q] = 0.f; acc[q] = 0.f; fi[q] = fs[i0 + q]; }
  for (int jt = 0; jt < TT; jt += 128) {
#pragma unroll
    for (int u = 0; u < 8; ++u) {
      int idx = tid + u * 256;
      int jj = idx >> 4, dq = (idx & 15) * 4;
      *(float4*)&Ht[jj][dq] =
          *(const float4*)&hgat[((size_t)(b * TT + jt + jj)) * HH + hd * HDIM + dq];
    }
    if (tid < 128) fd[tid] = fdp[jt + tid];
    __syncthreads();
#pragma unroll
    for (int q = 0; q < 8; ++q) {
      float e0 = fi[q] + fd[lane];      e0 = (e0 > 0.f) ? e0 : 0.2f * e0;
      float e1 = fi[q] + fd[lane + 64]; e1 = (e1 > 0.f) ? e1 : 0.2f * e1;
      float mn = fmaxf(m[q], wmax(fmaxf(e0, e1)));
      float corr = __expf(m[q] - mn);
      float p0 = __expf(e0 - mn), p1 = __expf(e1 - mn);
      l[q] = l[q] * corr + wsum(p0 + p1);
      m[q] = mn;
      acc[q] *= corr;
      pq[wave][lane][q] = p0;
      pq[wave][lane + 64][q] = p1;
    }
#pragma unroll 4
    for (int jj = 0; jj < 128; ++jj) {
      float4 pa = *(const float4*)&pq[wave][jj][0];
      float4 pb = *(const float4*)&pq[wave][jj][4];
      float hv = Ht[jj][lane];
      acc[0] += pa.x * hv; acc[1] += pa.y * hv; acc[2] += pa.z * hv; acc[3] += pa.w * hv;
      acc[4] += pb.x * hv; acc[5] += pb.y * hv; acc[6] += pb.z * hv; acc[7] += pb.w * hv;
    }
    __syncthreads();
  }
#pragma unroll
  for (int q = 0; q < 8; ++q)
    out[((size_t)(b * TT + i0 + q)) * HH + hd * HDIM + lane] = acc[q] / l[q];
}

// ---------------- residual + LayerNorm ----------------
__global__ __launch_bounds__(256) void ln_res(
    const float* __restrict__ g, const float* __restrict__ gat,
    const float* __restrict__ gamma, const float* __restrict__ beta,
    float* __restrict__ y) {
  int wave = threadIdx.x >> 6, lane = threadIdx.x & 63;
  size_t n = (size_t)blockIdx.x * 4 + wave;
  float4 v = ((const float4*)(g + n * HH))[lane];
  float4 w = ((const float4*)(gat + n * HH))[lane];
  v.x += w.x; v.y += w.y; v.z += w.z; v.w += w.w;
  float mu = wsum(v.x + v.y + v.z + v.w) * (1.f / 256.f);
  float dx = v.x - mu, dy = v.y - mu, dz = v.z - mu, dw = v.w - mu;
  float var = wsum(dx * dx + dy * dy + dz * dz + dw * dw) * (1.f / 256.f);
  float rstd = rsqrtf(var + 1e-5f);
  float4 gm = ((const float4*)gamma)[lane];
  float4 bt = ((const float4*)beta)[lane];
  float4 o = {dx * rstd * gm.x + bt.x, dy * rstd * gm.y + bt.y,
              dz * rstd * gm.z + bt.z, dw * rstd * gm.w + bt.w};
  ((float4*)(y + n * HH))[lane] = o;
}

// ---------------- MHA flash attention ----------------
// qkv[b,t,768] packed q|k|v; head hd dims hd*64..+63. K^T and V share an LDS
// buffer (staged in separate phases). scores scaled by 1/8.
__global__ __launch_bounds__(256) void mha_attn(const float* __restrict__ qkv,
                                                float* __restrict__ ctx) {
  __shared__ __align__(16) float KV[8320];        // K^T [64][130] | V [128][64]
  __shared__ __align__(16) float qq[4][64][8];
  __shared__ __align__(16) float pq[4][128][8];
  const int tid = threadIdx.x, wave = tid >> 6, lane = tid & 63;
  const int hd = blockIdx.y, b = blockIdx.z;
  const int i0 = blockIdx.x * 32 + wave * 8;
#pragma unroll
  for (int q = 0; q < 8; ++q)
    qq[wave][lane][q] = qkv[((size_t)(b * TT + i0 + q)) * H3 + hd * HDIM + lane];
  float m[8], l[8], acc[8];
#pragma unroll
  for (int q = 0; q < 8; ++q) { m[q] = -1e30f; l[q] = 0.f; acc[q] = 0.f; }
  for (int jt = 0; jt < TT; jt += 128) {
    // stage K^T: KV[dd*130 + j]
#pragma unroll
    for (int u = 0; u < 8; ++u) {
      int idx = tid + u * 256;
      int jj = idx >> 4, dq = (idx & 15) * 4;
      float4 kv = *(const float4*)&qkv[((size_t)(b * TT + jt + jj)) * H3 + HH + hd * HDIM + dq];
      KV[(dq + 0) * 130 + jj] = kv.x;
      KV[(dq + 1) * 130 + jj] = kv.y;
      KV[(dq + 2) * 130 + jj] = kv.z;
      KV[(dq + 3) * 130 + jj] = kv.w;
    }
    __syncthreads();
    float e0[8] = {}, e1[8] = {};
#pragma unroll 8
    for (int dd = 0; dd < 64; ++dd) {
      float4 qa = *(const float4*)&qq[wave][dd][0];
      float4 qb = *(const float4*)&qq[wave][dd][4];
      float k0 = KV[dd * 130 + lane], k1 = KV[dd * 130 + 64 + lane];
      e0[0] += qa.x * k0; e0[1] += qa.y * k0; e0[2] += qa.z * k0; e0[3] += qa.w * k0;
      e0[4] += qb.x * k0; e0[5] += qb.y * k0; e0[6] += qb.z * k0; e0[7] += qb.w * k0;
      e1[0] += qa.x * k1; e1[1] += qa.y * k1; e1[2] += qa.z * k1; e1[3] += qa.w * k1;
      e1[4] += qb.x * k1; e1[5] += qb.y * k1; e1[6] += qb.z * k1; e1[7] += qb.w * k1;
    }
    __syncthreads();  // done reading K^T
    // stage V over the same buffer: KV[j*64 + dd]
#pragma unroll
    for (int u = 0; u < 8; ++u) {
      int idx = tid + u * 256;
      int jj = idx >> 4, dq = (idx & 15) * 4;
      *(float4*)&KV[jj * 64 + dq] =
          *(const float4*)&qkv[((size_t)(b * TT + jt + jj)) * H3 + 2 * HH + hd * HDIM + dq];
    }
#pragma unroll
    for (int q = 0; q < 8; ++q) {
      float s0 = e0[q] * 0.125f, s1 = e1[q] * 0.125f;
      float mn = fmaxf(m[q], wmax(fmaxf(s0, s1)));
      float corr = __expf(m[q] - mn);
      float p0 = __expf(s0 - mn), p1 = __expf(s1 - mn);
      l[q] = l[q] * corr + wsum(p0 + p1);
      m[q] = mn;
      acc[q] *= corr;
      pq[wave][lane][q] = p0;
      pq[wave][lane + 64][q] = p1;
    }
    __syncthreads();  // V staged, pq written
#pragma unroll 4
    for (int jj = 0; jj < 128; ++jj) {
      float4 pa = *(const float4*)&pq[wave][jj][0];
      float4 pb = *(const float4*)&pq[wave][jj][4];
      float hv = KV[jj * 64 + lane];
      acc[0] += pa.x * hv; acc[1] += pa.y * hv; acc[2] += pa.z * hv; acc[3] += pa.w * hv;
      acc[4] += pb.x * hv; acc[5] += pb.y * hv; acc[6] += pb.z * hv; acc[7] += pb.w * hv;
    }
    __syncthreads();  // before next K^T overwrite
  }
#pragma unroll
  for (int q = 0; q < 8; ++q)
    ctx[((size_t)(b * TT + i0 + q)) * HH + hd * HDIM + lane] = acc[q] / l[q];
}

// ---------------- mean pool over T ----------------
__global__ void mean_pool(const float* __restrict__ x, float* __restrict__ out) {
  int b = blockIdx.x, j = threadIdx.x;
  const float* p = x + (size_t)b * TT * HH + j;
  float s = 0.f;
  for (int t = 0; t < TT; ++t) s += p[(size_t)t * HH];
  out[b * HH + j] = s * (1.f / 512.f);
}

// ---------------- FC layers ----------------
__global__ void fc1_k(const float* __restrict__ pooled, const float* __restrict__ w,
                      const float* __restrict__ bias, float* __restrict__ hid) {
  int b = blockIdx.x, o = threadIdx.x;  // 128 threads
  const float* pp = pooled + b * HH;
  const float* wp = w + o * HH;
  float s = 0.f;
#pragma unroll 4
  for (int k = 0; k < HH; ++k) s += pp[k] * wp[k];
  hid[b * 128 + o] = fmaxf(s + bias[o], 0.f);
}

__global__ void fc2_k(const float* __restrict__ hid, const float* __restrict__ w,
                      const float* __restrict__ bias, float* __restrict__ out) {
  int t = threadIdx.x;  // 256 = 32 m x 8 c
  int mm = t >> 3, c = t & 7;
  const float* hp = hid + mm * 128;
  const float* wp = w + c * 128;
  float s = 0.f;
#pragma unroll 4
  for (int k = 0; k < 128; ++k) s += hp[k] * wp[k];
  out[mm * 8 + c] = s + bias[c];
}

extern "C" void kernel_launch(void* const* d_in, const int* in_sizes, int n_in,
                              void* d_out, int out_size, void* d_ws, size_t ws_size,
                              hipStream_t stream) {
  (void)in_sizes; (void)n_in; (void)out_size; (void)ws_size;
  const float* x    = (const float*)d_in[0];
  const float* Wih0 = (const float*)d_in[1];
  const float* Whh0 = (const float*)d_in[2];
  const float* bih0 = (const float*)d_in[3];
  const float* bhh0 = (const float*)d_in[4];
  const float* Wih1 = (const float*)d_in[5];
  const float* Whh1 = (const float*)d_in[6];
  const float* bih1 = (const float*)d_in[7];
  const float* bhh1 = (const float*)d_in[8];
  const float* gatW = (const float*)d_in[9];
  const float* gatA = (const float*)d_in[10];
  const float* lng  = (const float*)d_in[11];
  const float* lnb  = (const float*)d_in[12];
  const float* inw  = (const float*)d_in[13];
  const float* inb  = (const float*)d_in[14];
  const float* outw = (const float*)d_in[15];
  const float* outb = (const float*)d_in[16];
  const float* f1w  = (const float*)d_in[17];
  const float* f1b  = (const float*)d_in[18];
  const float* f2w  = (const float*)d_in[19];
  const float* f2b  = (const float*)d_in[20];
  float* out = (float*)d_out;
  float* ws = (float*)d_ws;

  // workspace layout (floats), with reuse:
  //   XPA: xp0 -> xp1 -> qkv ; G0: gru0-out -> gat_out ; Yb: y -> attn_out ;
  //   HGAT: gat per-head feats -> mha ctx
  float* XPA   = ws;                  // 16384*768
  float* G0    = ws + 12582912;       // 16384*256
  float* G1    = G0 + 4194304;        // 16384*256
  float* Yb    = G1 + 4194304;        // 16384*256
  float* HGAT  = Yb + 4194304;        // 16384*256
  float* GATWT = HGAT + 4194304;      // 256*256
  float* FSRC  = GATWT + 65536;       // 32*4*512
  float* FDST  = FSRC + 65536;        // 32*4*512
  float* POOL  = FDST + 65536;        // 32*256
  float* HIDb  = POOL + 8192;         // 32*128

  // 1. xp0 = x @ W_ih0^T + b_ih0
  gemm_bt<<<dim3(6, 128), 256, 0, stream>>>(x, Wih0, bih0, XPA, 16384, 768, 128);
  // 2. GRU layer 0
  gru_layer<<<32, 1024, 0, stream>>>(XPA, Whh0, bhh0, G0);
  // 3. xp1 = g0 @ W_ih1^T + b_ih1
  gemm_bt<<<dim3(6, 128), 256, 0, stream>>>(G0, Wih1, bih1, XPA, 16384, 768, 256);
  // 4. GRU layer 1
  gru_layer<<<32, 1024, 0, stream>>>(XPA, Whh1, bhh1, G1);
  // 5. GAT weight transpose + per-head features + attention
  gat_wt<<<256, 256, 0, stream>>>(gatW, GATWT);
  gemm_bt<<<dim3(2, 128), 256, 0, stream>>>(G1, GATWT, nullptr, HGAT, 16384, 256, 256);
  gat_fsd<<<dim3(32, 4), 512, 0, stream>>>(HGAT, gatA, FSRC, FDST);
  gat_attn<<<dim3(16, 4, 32), 256, 0, stream>>>(HGAT, FSRC, FDST, G0);
  // 6. y = LN(g + gat_out)
  ln_res<<<4096, 256, 0, stream>>>(G1, G0, lng, lnb, Yb);
  // 7. MHA
  gemm_bt<<<dim3(6, 128), 256, 0, stream>>>(Yb, inw, inb, XPA, 16384, 768, 256);
  mha_attn<<<dim3(16, 4, 32), 256, 0, stream>>>(XPA, HGAT);
  gemm_bt<<<dim3(2, 128), 256, 0, stream>>>(HGAT, outw, outb, Yb, 16384, 256, 256);
  // 8. pool + FC head
  mean_pool<<<32, 256, 0, stream>>>(Yb, POOL);
  fc1_k<<<32, 128, 0, stream>>>(POOL, f1w, f1b, HIDb);
  fc2_k<<<1, 256, 0, stream>>>(HIDb, f2w, f2b, out);
}

// Round 3
// 2075.527 us; speedup vs baseline: 10.8174x; 5.5403x over previous
//
#include <hip/hip_runtime.h>
#include <math.h>

// Problem constants
#define BB 32
#define TT 512
#define INF_ 128
#define HH 256
#define H3 768
#define NHEADS 4
#define HDIM 64

typedef _Float16 half_t;
typedef half_t half2_t __attribute__((ext_vector_type(2)));

#if defined(__has_builtin)
#if __has_builtin(__builtin_amdgcn_fdot2)
#define FDOT2(a, b, c) __builtin_amdgcn_fdot2((a), (b), (c), false)
#endif
#endif
#ifndef FDOT2
#define FDOT2(a, b, c) fmaf((float)(a).x, (float)(b).x, fmaf((float)(a).y, (float)(b).y, (c)))
#endif

// ---------------- wave helpers (wave = 64 on CDNA) ----------------
__device__ __forceinline__ float wsum(float v) {
#pragma unroll
  for (int o = 32; o > 0; o >>= 1) v += __shfl_xor(v, o, 64);
  return v;
}
__device__ __forceinline__ float wmax(float v) {
#pragma unroll
  for (int o = 32; o > 0; o >>= 1) v = fmaxf(v, __shfl_xor(v, o, 64));
  return v;
}

// ---------------- GEMM: C[M,N] = A[M,K] * B[N,K]^T + bias ----------------
__global__ __launch_bounds__(256) void gemm_bt(
    const float* __restrict__ A, const float* __restrict__ Bw,
    const float* __restrict__ bias, float* __restrict__ C,
    int M, int N, int K) {
  __shared__ __align__(16) float As[16][132];
  __shared__ __align__(16) float Bs[16][132];
  const int tid = threadIdx.x;
  const int tx = tid & 15, ty = tid >> 4;
  const int m0 = blockIdx.y * 128, n0 = blockIdx.x * 128;
  const int r = tid >> 1, kc = (tid & 1) * 8;
  float acc[8][8] = {};
  for (int k0 = 0; k0 < K; k0 += 16) {
    float4 a0 = *(const float4*)(A + (size_t)(m0 + r) * K + k0 + kc);
    float4 a1 = *(const float4*)(A + (size_t)(m0 + r) * K + k0 + kc + 4);
    float4 b0 = *(const float4*)(Bw + (size_t)(n0 + r) * K + k0 + kc);
    float4 b1 = *(const float4*)(Bw + (size_t)(n0 + r) * K + k0 + kc + 4);
    __syncthreads();  // previous tile fully consumed
    As[kc + 0][r] = a0.x; As[kc + 1][r] = a0.y; As[kc + 2][r] = a0.z; As[kc + 3][r] = a0.w;
    As[kc + 4][r] = a1.x; As[kc + 5][r] = a1.y; As[kc + 6][r] = a1.z; As[kc + 7][r] = a1.w;
    Bs[kc + 0][r] = b0.x; Bs[kc + 1][r] = b0.y; Bs[kc + 2][r] = b0.z; Bs[kc + 3][r] = b0.w;
    Bs[kc + 4][r] = b1.x; Bs[kc + 5][r] = b1.y; Bs[kc + 6][r] = b1.z; Bs[kc + 7][r] = b1.w;
    __syncthreads();
#pragma unroll
    for (int kk = 0; kk < 16; ++kk) {
      float4 x0 = *(const float4*)&As[kk][ty * 8];
      float4 x1 = *(const float4*)&As[kk][ty * 8 + 4];
      float4 y0 = *(const float4*)&Bs[kk][tx * 8];
      float4 y1 = *(const float4*)&Bs[kk][tx * 8 + 4];
      float xa[8] = {x0.x, x0.y, x0.z, x0.w, x1.x, x1.y, x1.z, x1.w};
      float yb[8] = {y0.x, y0.y, y0.z, y0.w, y1.x, y1.y, y1.z, y1.w};
#pragma unroll
      for (int i = 0; i < 8; ++i)
#pragma unroll
        for (int j = 0; j < 8; ++j) acc[i][j] += xa[i] * yb[j];
    }
  }
  float bv[8];
#pragma unroll
  for (int j = 0; j < 8; ++j) bv[j] = bias ? bias[n0 + tx * 8 + j] : 0.f;
#pragma unroll
  for (int i = 0; i < 8; ++i) {
    float4 o0 = {acc[i][0] + bv[0], acc[i][1] + bv[1], acc[i][2] + bv[2], acc[i][3] + bv[3]};
    float4 o1 = {acc[i][4] + bv[4], acc[i][5] + bv[5], acc[i][6] + bv[6], acc[i][7] + bv[7]};
    float* cp = C + (size_t)(m0 + ty * 8 + i) * N + n0 + tx * 8;
    *(float4*)cp = o0;
    *(float4*)(cp + 4) = o1;
  }
}

// ---------------- GRU recurrence: fp16-packed register-resident W_hh ------
// One block (512 thr = 8 waves = 2 waves/SIMD, 256-VGPR cap) per batch.
// Thread (j,kh), tid = kh + 2*j: holds W_hh rows {j,256+j,512+j} cols
// [128*kh,+128) as 192 packed-f16 VGPRs (fits; round 2's fp32 plan spilled
// to scratch -> VGPR_Count=64, VALUBusy 2%). Inner product via
// v_dot2_f32_f16 (2 MAC/lane/cyc, fp32 accum). h lives packed-f16 in LDS:
// reads are 2-distinct-address broadcasts (free), write is one b32 per
// even-j producer. One barrier per step.
__global__ __launch_bounds__(512, 2) void gru_layer(
    const float* __restrict__ xp, const float* __restrict__ Whh,
    const float* __restrict__ bhh, float* __restrict__ out) {
  __shared__ __align__(16) half_t hs[2][256];
  const int tid = threadIdx.x;
  const int kh = tid & 1, j = tid >> 1;
  const int b = blockIdx.x;
  half2_t wr[64], wz[64], wn[64];
  {
    const float2* p0 = (const float2*)(Whh + (size_t)j * HH + kh * 128);
    const float2* p1 = (const float2*)(Whh + (size_t)(HH + j) * HH + kh * 128);
    const float2* p2 = (const float2*)(Whh + (size_t)(2 * HH + j) * HH + kh * 128);
#pragma unroll
    for (int i = 0; i < 64; ++i) {
      float2 v = p0[i]; wr[i] = half2_t{(half_t)v.x, (half_t)v.y};
    }
#pragma unroll
    for (int i = 0; i < 64; ++i) {
      float2 v = p1[i]; wz[i] = half2_t{(half_t)v.x, (half_t)v.y};
    }
#pragma unroll
    for (int i = 0; i < 64; ++i) {
      float2 v = p2[i]; wn[i] = half2_t{(half_t)v.x, (half_t)v.y};
    }
  }
  const float br = bhh[j], bz = bhh[HH + j], bn = bhh[2 * HH + j];
  for (int i = tid; i < 256; i += 512) ((unsigned int*)hs)[i] = 0u;
  __syncthreads();
  float hprev = 0.f;
  const float* xrow = xp + (size_t)b * TT * H3;
  float* orow = out + (size_t)b * TT * HH;
  float xr = xrow[j], xz = xrow[HH + j], xn = xrow[2 * HH + j];
  for (int t = 0; t < TT; ++t) {
    float nxr = 0.f, nxz = 0.f, nxn = 0.f;
    if (t + 1 < TT) {  // prefetch next step's xp (independent of h)
      const float* x2 = xrow + H3;
      nxr = x2[j]; nxz = x2[HH + j]; nxn = x2[2 * HH + j];
    }
    const float4* hp4 = (const float4*)&hs[t & 1][kh * 128];
    float ar = 0.f, az = 0.f, an = 0.f;
#pragma unroll
    for (int i = 0; i < 16; ++i) {
      float4 v = hp4[i];
      half2_t h2[4];
      *(float4*)h2 = v;
#pragma unroll
      for (int u = 0; u < 4; ++u) {
        ar = FDOT2(wr[4 * i + u], h2[u], ar);
        az = FDOT2(wz[4 * i + u], h2[u], az);
        an = FDOT2(wn[4 * i + u], h2[u], an);
      }
    }
    ar += __shfl_xor(ar, 1);
    az += __shfl_xor(az, 1);
    an += __shfl_xor(an, 1);
    float rg = 1.f / (1.f + __expf(-(xr + ar + br)));
    float zg = 1.f / (1.f + __expf(-(xz + az + bz)));
    float ng = 2.f / (1.f + __expf(-2.f * (xn + rg * (an + bn)))) - 1.f;  // tanh, inf-safe
    float hnew = (1.f - zg) * ng + zg * hprev;
    hprev = hnew;
    float hpart = __shfl_xor(hnew, 2);  // even-j lane gets h_{j+1}
    if ((tid & 3) == 0) {               // kh==0 && j even: pack pair, one b32 write
      half2_t pk;
      pk.x = (half_t)hnew;
      pk.y = (half_t)hpart;
      *(half2_t*)&hs[(t + 1) & 1][j] = pk;
    }
    if (kh == 0) orow[j] = hnew;
    __syncthreads();
    xr = nxr; xz = nxz; xn = nxn;
    xrow += H3; orow += HH;
  }
}

// ---------------- gat_W transpose: [4,256,64] -> [256 cols][256 k] ----------------
__global__ void gat_wt(const float* __restrict__ W, float* __restrict__ Wt) {
  int idx = blockIdx.x * 256 + threadIdx.x;  // [0, 65536)
  int col = idx >> 8, k = idx & 255;
  Wt[idx] = W[((size_t)((col >> 6) * HH + k)) * HDIM + (col & 63)];
}

// ---------------- GAT f_src/f_dst ----------------
__global__ void gat_fsd(const float* __restrict__ hgat, const float* __restrict__ a,
                        float* __restrict__ fsrc, float* __restrict__ fdst) {
  int b = blockIdx.x, hd = blockIdx.y, t = threadIdx.x;  // block 512
  const float* hp = hgat + ((size_t)(b * TT + t)) * HH + hd * HDIM;
  const float* ap = a + hd * 2 * HDIM;
  float fs = 0.f, fd = 0.f;
#pragma unroll 4
  for (int d = 0; d < HDIM; ++d) {
    float hv = hp[d];
    fs += hv * ap[d];
    fd += hv * ap[HDIM + d];
  }
  fsrc[(b * NHEADS + hd) * TT + t] = fs;
  fdst[(b * NHEADS + hd) * TT + t] = fd;
}

// ---------------- GAT flash attention ----------------
__global__ __launch_bounds__(256) void gat_attn(
    const float* __restrict__ hgat, const float* __restrict__ fsrc,
    const float* __restrict__ fdst, float* __restrict__ out) {
  __shared__ __align__(16) float Ht[128][64];
  __shared__ __align__(16) float fd[128];
  __shared__ __align__(16) float pq[4][128][8];
  const int tid = threadIdx.x, wave = tid >> 6, lane = tid & 63;
  const int hd = blockIdx.y, b = blockIdx.z;
  const int i0 = blockIdx.x * 32 + wave * 8;
  const float* fs = fsrc + (size_t)(b * NHEADS + hd) * TT;
  const float* fdp = fdst + (size_t)(b * NHEADS + hd) * TT;
  float m[8], l[8], acc[8], fi[8];
#pragma unroll
  for (int q = 0; q < 8; ++q) { m[q] = -1e30f; l[q] = 0.f; acc[q] = 0.f; fi[q] = fs[i0 + q]; }
  for (int jt = 0; jt < TT; jt += 128) {
#pragma unroll
    for (int u = 0; u < 8; ++u) {
      int idx = tid + u * 256;
      int jj = idx >> 4, dq = (idx & 15) * 4;
      *(float4*)&Ht[jj][dq] =
          *(const float4*)&hgat[((size_t)(b * TT + jt + jj)) * HH + hd * HDIM + dq];
    }
    if (tid < 128) fd[tid] = fdp[jt + tid];
    __syncthreads();
#pragma unroll
    for (int q = 0; q < 8; ++q) {
      float e0 = fi[q] + fd[lane];      e0 = (e0 > 0.f) ? e0 : 0.2f * e0;
      float e1 = fi[q] + fd[lane + 64]; e1 = (e1 > 0.f) ? e1 : 0.2f * e1;
      float mn = fmaxf(m[q], wmax(fmaxf(e0, e1)));
      float corr = __expf(m[q] - mn);
      float p0 = __expf(e0 - mn), p1 = __expf(e1 - mn);
      l[q] = l[q] * corr + wsum(p0 + p1);
      m[q] = mn;
      acc[q] *= corr;
      pq[wave][lane][q] = p0;
      pq[wave][lane + 64][q] = p1;
    }
#pragma unroll 4
    for (int jj = 0; jj < 128; ++jj) {
      float4 pa = *(const float4*)&pq[wave][jj][0];
      float4 pb = *(const float4*)&pq[wave][jj][4];
      float hv = Ht[jj][lane];
      acc[0] += pa.x * hv; acc[1] += pa.y * hv; acc[2] += pa.z * hv; acc[3] += pa.w * hv;
      acc[4] += pb.x * hv; acc[5] += pb.y * hv; acc[6] += pb.z * hv; acc[7] += pb.w * hv;
    }
    __syncthreads();
  }
#pragma unroll
  for (int q = 0; q < 8; ++q)
    out[((size_t)(b * TT + i0 + q)) * HH + hd * HDIM + lane] = acc[q] / l[q];
}

// ---------------- residual + LayerNorm ----------------
__global__ __launch_bounds__(256) void ln_res(
    const float* __restrict__ g, const float* __restrict__ gat,
    const float* __restrict__ gamma, const float* __restrict__ beta,
    float* __restrict__ y) {
  int wave = threadIdx.x >> 6, lane = threadIdx.x & 63;
  size_t n = (size_t)blockIdx.x * 4 + wave;
  float4 v = ((const float4*)(g + n * HH))[lane];
  float4 w = ((const float4*)(gat + n * HH))[lane];
  v.x += w.x; v.y += w.y; v.z += w.z; v.w += w.w;
  float mu = wsum(v.x + v.y + v.z + v.w) * (1.f / 256.f);
  float dx = v.x - mu, dy = v.y - mu, dz = v.z - mu, dw = v.w - mu;
  float var = wsum(dx * dx + dy * dy + dz * dz + dw * dw) * (1.f / 256.f);
  float rstd = rsqrtf(var + 1e-5f);
  float4 gm = ((const float4*)gamma)[lane];
  float4 bt = ((const float4*)beta)[lane];
  float4 o = {dx * rstd * gm.x + bt.x, dy * rstd * gm.y + bt.y,
              dz * rstd * gm.z + bt.z, dw * rstd * gm.w + bt.w};
  ((float4*)(y + n * HH))[lane] = o;
}

// ---------------- MHA flash attention ----------------
__global__ __launch_bounds__(256) void mha_attn(const float* __restrict__ qkv,
                                                float* __restrict__ ctx) {
  __shared__ __align__(16) float KV[8320];        // K^T [64][130] | V [128][64]
  __shared__ __align__(16) float qq[4][64][8];
  __shared__ __align__(16) float pq[4][128][8];
  const int tid = threadIdx.x, wave = tid >> 6, lane = tid & 63;
  const int hd = blockIdx.y, b = blockIdx.z;
  const int i0 = blockIdx.x * 32 + wave * 8;
#pragma unroll
  for (int q = 0; q < 8; ++q)
    qq[wave][lane][q] = qkv[((size_t)(b * TT + i0 + q)) * H3 + hd * HDIM + lane];
  float m[8], l[8], acc[8];
#pragma unroll
  for (int q = 0; q < 8; ++q) { m[q] = -1e30f; l[q] = 0.f; acc[q] = 0.f; }
  for (int jt = 0; jt < TT; jt += 128) {
    // stage K^T: KV[dd*130 + j]
#pragma unroll
    for (int u = 0; u < 8; ++u) {
      int idx = tid + u * 256;
      int jj = idx >> 4, dq = (idx & 15) * 4;
      float4 kv = *(const float4*)&qkv[((size_t)(b * TT + jt + jj)) * H3 + HH + hd * HDIM + dq];
      KV[(dq + 0) * 130 + jj] = kv.x;
      KV[(dq + 1) * 130 + jj] = kv.y;
      KV[(dq + 2) * 130 + jj] = kv.z;
      KV[(dq + 3) * 130 + jj] = kv.w;
    }
    __syncthreads();
    float e0[8] = {}, e1[8] = {};
#pragma unroll 8
    for (int dd = 0; dd < 64; ++dd) {
      float4 qa = *(const float4*)&qq[wave][dd][0];
      float4 qb = *(const float4*)&qq[wave][dd][4];
      float k0 = KV[dd * 130 + lane], k1 = KV[dd * 130 + 64 + lane];
      e0[0] += qa.x * k0; e0[1] += qa.y * k0; e0[2] += qa.z * k0; e0[3] += qa.w * k0;
      e0[4] += qb.x * k0; e0[5] += qb.y * k0; e0[6] += qb.z * k0; e0[7] += qb.w * k0;
      e1[0] += qa.x * k1; e1[1] += qa.y * k1; e1[2] += qa.z * k1; e1[3] += qa.w * k1;
      e1[4] += qb.x * k1; e1[5] += qb.y * k1; e1[6] += qb.z * k1; e1[7] += qb.w * k1;
    }
    __syncthreads();  // done reading K^T
    // stage V over the same buffer: KV[j*64 + dd]
#pragma unroll
    for (int u = 0; u < 8; ++u) {
      int idx = tid + u * 256;
      int jj = idx >> 4, dq = (idx & 15) * 4;
      *(float4*)&KV[jj * 64 + dq] =
          *(const float4*)&qkv[((size_t)(b * TT + jt + jj)) * H3 + 2 * HH + hd * HDIM + dq];
    }
#pragma unroll
    for (int q = 0; q < 8; ++q) {
      float s0 = e0[q] * 0.125f, s1 = e1[q] * 0.125f;
      float mn = fmaxf(m[q], wmax(fmaxf(s0, s1)));
      float corr = __expf(m[q] - mn);
      float p0 = __expf(s0 - mn), p1 = __expf(s1 - mn);
      l[q] = l[q] * corr + wsum(p0 + p1);
      m[q] = mn;
      acc[q] *= corr;
      pq[wave][lane][q] = p0;
      pq[wave][lane + 64][q] = p1;
    }
    __syncthreads();  // V staged, pq written
#pragma unroll 4
    for (int jj = 0; jj < 128; ++jj) {
      float4 pa = *(const float4*)&pq[wave][jj][0];
      float4 pb = *(const float4*)&pq[wave][jj][4];
      float hv = KV[jj * 64 + lane];
      acc[0] += pa.x * hv; acc[1] += pa.y * hv; acc[2] += pa.z * hv; acc[3] += pa.w * hv;
      acc[4] += pb.x * hv; acc[5] += pb.y * hv; acc[6] += pb.z * hv; acc[7] += pb.w * hv;
    }
    __syncthreads();  // before next K^T overwrite
  }
#pragma unroll
  for (int q = 0; q < 8; ++q)
    ctx[((size_t)(b * TT + i0 + q)) * HH + hd * HDIM + lane] = acc[q] / l[q];
}

// ---------------- mean pool over T ----------------
__global__ void mean_pool(const float* __restrict__ x, float* __restrict__ out) {
  int b = blockIdx.x, j = threadIdx.x;
  const float* p = x + (size_t)b * TT * HH + j;
  float s = 0.f;
  for (int t = 0; t < TT; ++t) s += p[(size_t)t * HH];
  out[b * HH + j] = s * (1.f / 512.f);
}

// ---------------- FC layers ----------------
__global__ void fc1_k(const float* __restrict__ pooled, const float* __restrict__ w,
                      const float* __restrict__ bias, float* __restrict__ hid) {
  int b = blockIdx.x, o = threadIdx.x;  // 128 threads
  const float* pp = pooled + b * HH;
  const float* wp = w + o * HH;
  float s = 0.f;
#pragma unroll 4
  for (int k = 0; k < HH; ++k) s += pp[k] * wp[k];
  hid[b * 128 + o] = fmaxf(s + bias[o], 0.f);
}

__global__ void fc2_k(const float* __restrict__ hid, const float* __restrict__ w,
                      const float* __restrict__ bias, float* __restrict__ out) {
  int t = threadIdx.x;  // 256 = 32 m x 8 c
  int mm = t >> 3, c = t & 7;
  const float* hp = hid + mm * 128;
  const float* wp = w + c * 128;
  float s = 0.f;
#pragma unroll 4
  for (int k = 0; k < 128; ++k) s += hp[k] * wp[k];
  out[mm * 8 + c] = s + bias[c];
}

extern "C" void kernel_launch(void* const* d_in, const int* in_sizes, int n_in,
                              void* d_out, int out_size, void* d_ws, size_t ws_size,
                              hipStream_t stream) {
  (void)in_sizes; (void)n_in; (void)out_size; (void)ws_size;
  const float* x    = (const float*)d_in[0];
  const float* Wih0 = (const float*)d_in[1];
  const float* Whh0 = (const float*)d_in[2];
  const float* bih0 = (const float*)d_in[3];
  const float* bhh0 = (const float*)d_in[4];
  const float* Wih1 = (const float*)d_in[5];
  const float* Whh1 = (const float*)d_in[6];
  const float* bih1 = (const float*)d_in[7];
  const float* bhh1 = (const float*)d_in[8];
  const float* gatW = (const float*)d_in[9];
  const float* gatA = (const float*)d_in[10];
  const float* lng  = (const float*)d_in[11];
  const float* lnb  = (const float*)d_in[12];
  const float* inw  = (const float*)d_in[13];
  const float* inb  = (const float*)d_in[14];
  const float* outw = (const float*)d_in[15];
  const float* outb = (const float*)d_in[16];
  const float* f1w  = (const float*)d_in[17];
  const float* f1b  = (const float*)d_in[18];
  const float* f2w  = (const float*)d_in[19];
  const float* f2b  = (const float*)d_in[20];
  float* out = (float*)d_out;
  float* ws = (float*)d_ws;

  // workspace layout (floats), with reuse:
  //   XPA: xp0 -> xp1 -> qkv ; G0: gru0-out -> gat_out ; Yb: y -> attn_out ;
  //   HGAT: gat per-head feats -> mha ctx
  float* XPA   = ws;                  // 16384*768
  float* G0    = ws + 12582912;       // 16384*256
  float* G1    = G0 + 4194304;        // 16384*256
  float* Yb    = G1 + 4194304;        // 16384*256
  float* HGAT  = Yb + 4194304;        // 16384*256
  float* GATWT = HGAT + 4194304;      // 256*256
  float* FSRC  = GATWT + 65536;       // 32*4*512
  float* FDST  = FSRC + 65536;        // 32*4*512
  float* POOL  = FDST + 65536;        // 32*256
  float* HIDb  = POOL + 8192;         // 32*128

  // 1. xp0 = x @ W_ih0^T + b_ih0
  gemm_bt<<<dim3(6, 128), 256, 0, stream>>>(x, Wih0, bih0, XPA, 16384, 768, 128);
  // 2. GRU layer 0
  gru_layer<<<32, 512, 0, stream>>>(XPA, Whh0, bhh0, G0);
  // 3. xp1 = g0 @ W_ih1^T + b_ih1
  gemm_bt<<<dim3(6, 128), 256, 0, stream>>>(G0, Wih1, bih1, XPA, 16384, 768, 256);
  // 4. GRU layer 1
  gru_layer<<<32, 512, 0, stream>>>(XPA, Whh1, bhh1, G1);
  // 5. GAT weight transpose + per-head features + attention
  gat_wt<<<256, 256, 0, stream>>>(gatW, GATWT);
  gemm_bt<<<dim3(2, 128), 256, 0, stream>>>(G1, GATWT, nullptr, HGAT, 16384, 256, 256);
  gat_fsd<<<dim3(32, 4), 512, 0, stream>>>(HGAT, gatA, FSRC, FDST);
  gat_attn<<<dim3(16, 4, 32), 256, 0, stream>>>(HGAT, FSRC, FDST, G0);
  // 6. y = LN(g + gat_out)
  ln_res<<<4096, 256, 0, stream>>>(G1, G0, lng, lnb, Yb);
  // 7. MHA
  gemm_bt<<<dim3(6, 128), 256, 0, stream>>>(Yb, inw, inb, XPA, 16384, 768, 256);
  mha_attn<<<dim3(16, 4, 32), 256, 0, stream>>>(XPA, HGAT);
  gemm_bt<<<dim3(2, 128), 256, 0, stream>>>(HGAT, outw, outb, Yb, 16384, 256, 256);
  // 8. pool + FC head
  mean_pool<<<32, 256, 0, stream>>>(Yb, POOL);
  fc1_k<<<32, 128, 0, stream>>>(POOL, f1w, f1b, HIDb);
  fc2_k<<<1, 256, 0, stream>>>(HIDb, f2w, f2b, out);
}

// Round 4
// 2031.573 us; speedup vs baseline: 11.0515x; 1.0216x over previous
//
#include <hip/hip_runtime.h>
#include <math.h>

// Problem constants
#define BB 32
#define TT 512
#define INF_ 128
#define HH 256
#define H3 768
#define NHEADS 4
#define HDIM 64

typedef _Float16 half_t;
typedef half_t half2_t __attribute__((ext_vector_type(2)));

#if defined(__has_builtin)
#if __has_builtin(__builtin_amdgcn_fdot2)
#define FDOT2(a, b, c) __builtin_amdgcn_fdot2((a), (b), (c), false)
#endif
#endif
#ifndef FDOT2
#define FDOT2(a, b, c) fmaf((float)(a).x, (float)(b).x, fmaf((float)(a).y, (float)(b).y, (c)))
#endif

// ---------------- wave helpers (wave = 64 on CDNA) ----------------
__device__ __forceinline__ float wsum(float v) {
#pragma unroll
  for (int o = 32; o > 0; o >>= 1) v += __shfl_xor(v, o, 64);
  return v;
}
__device__ __forceinline__ float wmax(float v) {
#pragma unroll
  for (int o = 32; o > 0; o >>= 1) v = fmaxf(v, __shfl_xor(v, o, 64));
  return v;
}

// ---------------- GEMM: C[M,N] = A[M,K] * B[N,K]^T + bias ----------------
__global__ __launch_bounds__(256) void gemm_bt(
    const float* __restrict__ A, const float* __restrict__ Bw,
    const float* __restrict__ bias, float* __restrict__ C,
    int M, int N, int K) {
  __shared__ __align__(16) float As[16][132];
  __shared__ __align__(16) float Bs[16][132];
  const int tid = threadIdx.x;
  const int tx = tid & 15, ty = tid >> 4;
  const int m0 = blockIdx.y * 128, n0 = blockIdx.x * 128;
  const int r = tid >> 1, kc = (tid & 1) * 8;
  float acc[8][8] = {};
  for (int k0 = 0; k0 < K; k0 += 16) {
    float4 a0 = *(const float4*)(A + (size_t)(m0 + r) * K + k0 + kc);
    float4 a1 = *(const float4*)(A + (size_t)(m0 + r) * K + k0 + kc + 4);
    float4 b0 = *(const float4*)(Bw + (size_t)(n0 + r) * K + k0 + kc);
    float4 b1 = *(const float4*)(Bw + (size_t)(n0 + r) * K + k0 + kc + 4);
    __syncthreads();  // previous tile fully consumed
    As[kc + 0][r] = a0.x; As[kc + 1][r] = a0.y; As[kc + 2][r] = a0.z; As[kc + 3][r] = a0.w;
    As[kc + 4][r] = a1.x; As[kc + 5][r] = a1.y; As[kc + 6][r] = a1.z; As[kc + 7][r] = a1.w;
    Bs[kc + 0][r] = b0.x; Bs[kc + 1][r] = b0.y; Bs[kc + 2][r] = b0.z; Bs[kc + 3][r] = b0.w;
    Bs[kc + 4][r] = b1.x; Bs[kc + 5][r] = b1.y; Bs[kc + 6][r] = b1.z; Bs[kc + 7][r] = b1.w;
    __syncthreads();
#pragma unroll
    for (int kk = 0; kk < 16; ++kk) {
      float4 x0 = *(const float4*)&As[kk][ty * 8];
      float4 x1 = *(const float4*)&As[kk][ty * 8 + 4];
      float4 y0 = *(const float4*)&Bs[kk][tx * 8];
      float4 y1 = *(const float4*)&Bs[kk][tx * 8 + 4];
      float xa[8] = {x0.x, x0.y, x0.z, x0.w, x1.x, x1.y, x1.z, x1.w};
      float yb[8] = {y0.x, y0.y, y0.z, y0.w, y1.x, y1.y, y1.z, y1.w};
#pragma unroll
      for (int i = 0; i < 8; ++i)
#pragma unroll
        for (int j = 0; j < 8; ++j) acc[i][j] += xa[i] * yb[j];
    }
  }
  float bv[8];
#pragma unroll
  for (int j = 0; j < 8; ++j) bv[j] = bias ? bias[n0 + tx * 8 + j] : 0.f;
#pragma unroll
  for (int i = 0; i < 8; ++i) {
    float4 o0 = {acc[i][0] + bv[0], acc[i][1] + bv[1], acc[i][2] + bv[2], acc[i][3] + bv[3]};
    float4 o1 = {acc[i][4] + bv[4], acc[i][5] + bv[5], acc[i][6] + bv[6], acc[i][7] + bv[7]};
    float* cp = C + (size_t)(m0 + ty * 8 + i) * N + n0 + tx * 8;
    *(float4*)cp = o0;
    *(float4*)(cp + 4) = o1;
  }
}

// ---------------- GRU recurrence: fp16-packed register-resident W_hh ------
// One block (512 thr = 8 waves) per batch. Thread (j,kh), tid = kh + 2*j:
// holds W_hh rows {j,256+j,512+j} cols [128*kh,+128) as 192 packed-f16 VGPRs.
// EMPIRICAL (R2: LB(1024,4)->VGPR 64; R3: LB(512,2)->VGPR 128): this
// toolchain treats the 2nd __launch_bounds__ arg CUDA-style as min BLOCKS
// per CU. LB(512,1) -> 1 block/CU -> 2 waves/SIMD -> 256-VGPR cap, so the
// 192 weight regs fit without spilling (R3 spilled 64 of them -> 33 GB of
// scratch FETCH). h is packed-f16 in LDS [2 bufs][2 kh][144 halves]: the
// +32B pad puts kh=1 on banks 8..11 vs kh=0 on 0..3 -> no b128 2-way
// serialization (R3: 8.4M SQ_LDS_BANK_CONFLICT). Unpack via bit_cast, not
// memory punning, so SROA keeps temps in regs. One barrier per step.
__global__ __launch_bounds__(512, 1) void gru_layer(
    const float* __restrict__ xp, const float* __restrict__ Whh,
    const float* __restrict__ bhh, float* __restrict__ out) {
  __shared__ __align__(16) half_t hs[2][2][144];
  const int tid = threadIdx.x;
  const int kh = tid & 1, j = tid >> 1;
  const int b = blockIdx.x;
  half2_t wr[64], wz[64], wn[64];
  {
    const float2* p0 = (const float2*)(Whh + (size_t)j * HH + kh * 128);
    const float2* p1 = (const float2*)(Whh + (size_t)(HH + j) * HH + kh * 128);
    const float2* p2 = (const float2*)(Whh + (size_t)(2 * HH + j) * HH + kh * 128);
#pragma unroll
    for (int i = 0; i < 64; ++i) {
      float2 v = p0[i]; wr[i] = half2_t{(half_t)v.x, (half_t)v.y};
    }
#pragma unroll
    for (int i = 0; i < 64; ++i) {
      float2 v = p1[i]; wz[i] = half2_t{(half_t)v.x, (half_t)v.y};
    }
#pragma unroll
    for (int i = 0; i < 64; ++i) {
      float2 v = p2[i]; wn[i] = half2_t{(half_t)v.x, (half_t)v.y};
    }
  }
  const float br = bhh[j], bz = bhh[HH + j], bn = bhh[2 * HH + j];
  for (int i = tid; i < 2 * 2 * 144 / 2; i += 512) ((unsigned int*)hs)[i] = 0u;
  __syncthreads();
  float hprev = 0.f;
  const float* xrow = xp + (size_t)b * TT * H3;
  float* orow = out + (size_t)b * TT * HH;
  float xr = xrow[j], xz = xrow[HH + j], xn = xrow[2 * HH + j];
  for (int t = 0; t < TT; ++t) {
    float nxr = 0.f, nxz = 0.f, nxn = 0.f;
    if (t + 1 < TT) {  // prefetch next step's xp (independent of h)
      const float* x2 = xrow + H3;
      nxr = x2[j]; nxz = x2[HH + j]; nxn = x2[2 * HH + j];
    }
    const float4* hp4 = (const float4*)&hs[t & 1][kh][0];
    float ar = 0.f, az = 0.f, an = 0.f;
#pragma unroll
    for (int i = 0; i < 16; ++i) {
      float4 v = hp4[i];
      half2_t h0 = __builtin_bit_cast(half2_t, v.x);
      half2_t h1 = __builtin_bit_cast(half2_t, v.y);
      half2_t h2 = __builtin_bit_cast(half2_t, v.z);
      half2_t h3 = __builtin_bit_cast(half2_t, v.w);
      ar = FDOT2(wr[4 * i + 0], h0, ar);
      az = FDOT2(wz[4 * i + 0], h0, az);
      an = FDOT2(wn[4 * i + 0], h0, an);
      ar = FDOT2(wr[4 * i + 1], h1, ar);
      az = FDOT2(wz[4 * i + 1], h1, az);
      an = FDOT2(wn[4 * i + 1], h1, an);
      ar = FDOT2(wr[4 * i + 2], h2, ar);
      az = FDOT2(wz[4 * i + 2], h2, az);
      an = FDOT2(wn[4 * i + 2], h2, an);
      ar = FDOT2(wr[4 * i + 3], h3, ar);
      az = FDOT2(wz[4 * i + 3], h3, az);
      an = FDOT2(wn[4 * i + 3], h3, an);
    }
    ar += __shfl_xor(ar, 1);
    az += __shfl_xor(az, 1);
    an += __shfl_xor(an, 1);
    float rg = 1.f / (1.f + __expf(-(xr + ar + br)));
    float zg = 1.f / (1.f + __expf(-(xz + az + bz)));
    float ng = 2.f / (1.f + __expf(-2.f * (xn + rg * (an + bn)))) - 1.f;  // tanh, inf-safe
    float hnew = (1.f - zg) * ng + zg * hprev;
    hprev = hnew;
    float hpart = __shfl_xor(hnew, 2);  // even-j lane gets h_{j+1}
    if ((tid & 3) == 0) {               // kh==0 && j even: pack pair, one b32 write
      half2_t pk;
      pk.x = (half_t)hnew;
      pk.y = (half_t)hpart;
      *(half2_t*)&hs[(t + 1) & 1][j >> 7][j & 127] = pk;
    }
    if (kh == 0) orow[j] = hnew;
    __syncthreads();
    xr = nxr; xz = nxz; xn = nxn;
    xrow += H3; orow += HH;
  }
}

// ---------------- gat_W transpose: [4,256,64] -> [256 cols][256 k] ----------------
__global__ void gat_wt(const float* __restrict__ W, float* __restrict__ Wt) {
  int idx = blockIdx.x * 256 + threadIdx.x;  // [0, 65536)
  int col = idx >> 8, k = idx & 255;
  Wt[idx] = W[((size_t)((col >> 6) * HH + k)) * HDIM + (col & 63)];
}

// ---------------- GAT f_src/f_dst ----------------
__global__ void gat_fsd(const float* __restrict__ hgat, const float* __restrict__ a,
                        float* __restrict__ fsrc, float* __restrict__ fdst) {
  int b = blockIdx.x, hd = blockIdx.y, t = threadIdx.x;  // block 512
  const float* hp = hgat + ((size_t)(b * TT + t)) * HH + hd * HDIM;
  const float* ap = a + hd * 2 * HDIM;
  float fs = 0.f, fd = 0.f;
#pragma unroll 4
  for (int d = 0; d < HDIM; ++d) {
    float hv = hp[d];
    fs += hv * ap[d];
    fd += hv * ap[HDIM + d];
  }
  fsrc[(b * NHEADS + hd) * TT + t] = fs;
  fdst[(b * NHEADS + hd) * TT + t] = fd;
}

// ---------------- GAT flash attention ----------------
__global__ __launch_bounds__(256) void gat_attn(
    const float* __restrict__ hgat, const float* __restrict__ fsrc,
    const float* __restrict__ fdst, float* __restrict__ out) {
  __shared__ __align__(16) float Ht[128][64];
  __shared__ __align__(16) float fd[128];
  __shared__ __align__(16) float pq[4][128][8];
  const int tid = threadIdx.x, wave = tid >> 6, lane = tid & 63;
  const int hd = blockIdx.y, b = blockIdx.z;
  const int i0 = blockIdx.x * 32 + wave * 8;
  const float* fs = fsrc + (size_t)(b * NHEADS + hd) * TT;
  const float* fdp = fdst + (size_t)(b * NHEADS + hd) * TT;
  float m[8], l[8], acc[8], fi[8];
#pragma unroll
  for (int q = 0; q < 8; ++q) { m[q] = -1e30f; l[q] = 0.f; acc[q] = 0.f; fi[q] = fs[i0 + q]; }
  for (int jt = 0; jt < TT; jt += 128) {
#pragma unroll
    for (int u = 0; u < 8; ++u) {
      int idx = tid + u * 256;
      int jj = idx >> 4, dq = (idx & 15) * 4;
      *(float4*)&Ht[jj][dq] =
          *(const float4*)&hgat[((size_t)(b * TT + jt + jj)) * HH + hd * HDIM + dq];
    }
    if (tid < 128) fd[tid] = fdp[jt + tid];
    __syncthreads();
#pragma unroll
    for (int q = 0; q < 8; ++q) {
      float e0 = fi[q] + fd[lane];      e0 = (e0 > 0.f) ? e0 : 0.2f * e0;
      float e1 = fi[q] + fd[lane + 64]; e1 = (e1 > 0.f) ? e1 : 0.2f * e1;
      float mn = fmaxf(m[q], wmax(fmaxf(e0, e1)));
      float corr = __expf(m[q] - mn);
      float p0 = __expf(e0 - mn), p1 = __expf(e1 - mn);
      l[q] = l[q] * corr + wsum(p0 + p1);
      m[q] = mn;
      acc[q] *= corr;
      pq[wave][lane][q] = p0;
      pq[wave][lane + 64][q] = p1;
    }
#pragma unroll 4
    for (int jj = 0; jj < 128; ++jj) {
      float4 pa = *(const float4*)&pq[wave][jj][0];
      float4 pb = *(const float4*)&pq[wave][jj][4];
      float hv = Ht[jj][lane];
      acc[0] += pa.x * hv; acc[1] += pa.y * hv; acc[2] += pa.z * hv; acc[3] += pa.w * hv;
      acc[4] += pb.x * hv; acc[5] += pb.y * hv; acc[6] += pb.z * hv; acc[7] += pb.w * hv;
    }
    __syncthreads();
  }
#pragma unroll
  for (int q = 0; q < 8; ++q)
    out[((size_t)(b * TT + i0 + q)) * HH + hd * HDIM + lane] = acc[q] / l[q];
}

// ---------------- residual + LayerNorm ----------------
__global__ __launch_bounds__(256) void ln_res(
    const float* __restrict__ g, const float* __restrict__ gat,
    const float* __restrict__ gamma, const float* __restrict__ beta,
    float* __restrict__ y) {
  int wave = threadIdx.x >> 6, lane = threadIdx.x & 63;
  size_t n = (size_t)blockIdx.x * 4 + wave;
  float4 v = ((const float4*)(g + n * HH))[lane];
  float4 w = ((const float4*)(gat + n * HH))[lane];
  v.x += w.x; v.y += w.y; v.z += w.z; v.w += w.w;
  float mu = wsum(v.x + v.y + v.z + v.w) * (1.f / 256.f);
  float dx = v.x - mu, dy = v.y - mu, dz = v.z - mu, dw = v.w - mu;
  float var = wsum(dx * dx + dy * dy + dz * dz + dw * dw) * (1.f / 256.f);
  float rstd = rsqrtf(var + 1e-5f);
  float4 gm = ((const float4*)gamma)[lane];
  float4 bt = ((const float4*)beta)[lane];
  float4 o = {dx * rstd * gm.x + bt.x, dy * rstd * gm.y + bt.y,
              dz * rstd * gm.z + bt.z, dw * rstd * gm.w + bt.w};
  ((float4*)(y + n * HH))[lane] = o;
}

// ---------------- MHA flash attention ----------------
__global__ __launch_bounds__(256) void mha_attn(const float* __restrict__ qkv,
                                                float* __restrict__ ctx) {
  __shared__ __align__(16) float KV[8320];        // K^T [64][130] | V [128][64]
  __shared__ __align__(16) float qq[4][64][8];
  __shared__ __align__(16) float pq[4][128][8];
  const int tid = threadIdx.x, wave = tid >> 6, lane = tid & 63;
  const int hd = blockIdx.y, b = blockIdx.z;
  const int i0 = blockIdx.x * 32 + wave * 8;
#pragma unroll
  for (int q = 0; q < 8; ++q)
    qq[wave][lane][q] = qkv[((size_t)(b * TT + i0 + q)) * H3 + hd * HDIM + lane];
  float m[8], l[8], acc[8];
#pragma unroll
  for (int q = 0; q < 8; ++q) { m[q] = -1e30f; l[q] = 0.f; acc[q] = 0.f; }
  for (int jt = 0; jt < TT; jt += 128) {
    // stage K^T: KV[dd*130 + j]
#pragma unroll
    for (int u = 0; u < 8; ++u) {
      int idx = tid + u * 256;
      int jj = idx >> 4, dq = (idx & 15) * 4;
      float4 kv = *(const float4*)&qkv[((size_t)(b * TT + jt + jj)) * H3 + HH + hd * HDIM + dq];
      KV[(dq + 0) * 130 + jj] = kv.x;
      KV[(dq + 1) * 130 + jj] = kv.y;
      KV[(dq + 2) * 130 + jj] = kv.z;
      KV[(dq + 3) * 130 + jj] = kv.w;
    }
    __syncthreads();
    float e0[8] = {}, e1[8] = {};
#pragma unroll 8
    for (int dd = 0; dd < 64; ++dd) {
      float4 qa = *(const float4*)&qq[wave][dd][0];
      float4 qb = *(const float4*)&qq[wave][dd][4];
      float k0 = KV[dd * 130 + lane], k1 = KV[dd * 130 + 64 + lane];
      e0[0] += qa.x * k0; e0[1] += qa.y * k0; e0[2] += qa.z * k0; e0[3] += qa.w * k0;
      e0[4] += qb.x * k0; e0[5] += qb.y * k0; e0[6] += qb.z * k0; e0[7] += qb.w * k0;
      e1[0] += qa.x * k1; e1[1] += qa.y * k1; e1[2] += qa.z * k1; e1[3] += qa.w * k1;
      e1[4] += qb.x * k1; e1[5] += qb.y * k1; e1[6] += qb.z * k1; e1[7] += qb.w * k1;
    }
    __syncthreads();  // done reading K^T
    // stage V over the same buffer: KV[j*64 + dd]
#pragma unroll
    for (int u = 0; u < 8; ++u) {
      int idx = tid + u * 256;
      int jj = idx >> 4, dq = (idx & 15) * 4;
      *(float4*)&KV[jj * 64 + dq] =
          *(const float4*)&qkv[((size_t)(b * TT + jt + jj)) * H3 + 2 * HH + hd * HDIM + dq];
    }
#pragma unroll
    for (int q = 0; q < 8; ++q) {
      float s0 = e0[q] * 0.125f, s1 = e1[q] * 0.125f;
      float mn = fmaxf(m[q], wmax(fmaxf(s0, s1)));
      float corr = __expf(m[q] - mn);
      float p0 = __expf(s0 - mn), p1 = __expf(s1 - mn);
      l[q] = l[q] * corr + wsum(p0 + p1);
      m[q] = mn;
      acc[q] *= corr;
      pq[wave][lane][q] = p0;
      pq[wave][lane + 64][q] = p1;
    }
    __syncthreads();  // V staged, pq written
#pragma unroll 4
    for (int jj = 0; jj < 128; ++jj) {
      float4 pa = *(const float4*)&pq[wave][jj][0];
      float4 pb = *(const float4*)&pq[wave][jj][4];
      float hv = KV[jj * 64 + lane];
      acc[0] += pa.x * hv; acc[1] += pa.y * hv; acc[2] += pa.z * hv; acc[3] += pa.w * hv;
      acc[4] += pb.x * hv; acc[5] += pb.y * hv; acc[6] += pb.z * hv; acc[7] += pb.w * hv;
    }
    __syncthreads();  // before next K^T overwrite
  }
#pragma unroll
  for (int q = 0; q < 8; ++q)
    ctx[((size_t)(b * TT + i0 + q)) * HH + hd * HDIM + lane] = acc[q] / l[q];
}

// ---------------- mean pool over T ----------------
__global__ void mean_pool(const float* __restrict__ x, float* __restrict__ out) {
  int b = blockIdx.x, j = threadIdx.x;
  const float* p = x + (size_t)b * TT * HH + j;
  float s = 0.f;
  for (int t = 0; t < TT; ++t) s += p[(size_t)t * HH];
  out[b * HH + j] = s * (1.f / 512.f);
}

// ---------------- FC layers ----------------
__global__ void fc1_k(const float* __restrict__ pooled, const float* __restrict__ w,
                      const float* __restrict__ bias, float* __restrict__ hid) {
  int b = blockIdx.x, o = threadIdx.x;  // 128 threads
  const float* pp = pooled + b * HH;
  const float* wp = w + o * HH;
  float s = 0.f;
#pragma unroll 4
  for (int k = 0; k < HH; ++k) s += pp[k] * wp[k];
  hid[b * 128 + o] = fmaxf(s + bias[o], 0.f);
}

__global__ void fc2_k(const float* __restrict__ hid, const float* __restrict__ w,
                      const float* __restrict__ bias, float* __restrict__ out) {
  int t = threadIdx.x;  // 256 = 32 m x 8 c
  int mm = t >> 3, c = t & 7;
  const float* hp = hid + mm * 128;
  const float* wp = w + c * 128;
  float s = 0.f;
#pragma unroll 4
  for (int k = 0; k < 128; ++k) s += hp[k] * wp[k];
  out[mm * 8 + c] = s + bias[c];
}

extern "C" void kernel_launch(void* const* d_in, const int* in_sizes, int n_in,
                              void* d_out, int out_size, void* d_ws, size_t ws_size,
                              hipStream_t stream) {
  (void)in_sizes; (void)n_in; (void)out_size; (void)ws_size;
  const float* x    = (const float*)d_in[0];
  const float* Wih0 = (const float*)d_in[1];
  const float* Whh0 = (const float*)d_in[2];
  const float* bih0 = (const float*)d_in[3];
  const float* bhh0 = (const float*)d_in[4];
  const float* Wih1 = (const float*)d_in[5];
  const float* Whh1 = (const float*)d_in[6];
  const float* bih1 = (const float*)d_in[7];
  const float* bhh1 = (const float*)d_in[8];
  const float* gatW = (const float*)d_in[9];
  const float* gatA = (const float*)d_in[10];
  const float* lng  = (const float*)d_in[11];
  const float* lnb  = (const float*)d_in[12];
  const float* inw  = (const float*)d_in[13];
  const float* inb  = (const float*)d_in[14];
  const float* outw = (const float*)d_in[15];
  const float* outb = (const float*)d_in[16];
  const float* f1w  = (const float*)d_in[17];
  const float* f1b  = (const float*)d_in[18];
  const float* f2w  = (const float*)d_in[19];
  const float* f2b  = (const float*)d_in[20];
  float* out = (float*)d_out;
  float* ws = (float*)d_ws;

  // workspace layout (floats), with reuse:
  //   XPA: xp0 -> xp1 -> qkv ; G0: gru0-out -> gat_out ; Yb: y -> attn_out ;
  //   HGAT: gat per-head feats -> mha ctx
  float* XPA   = ws;                  // 16384*768
  float* G0    = ws + 12582912;       // 16384*256
  float* G1    = G0 + 4194304;        // 16384*256
  float* Yb    = G1 + 4194304;        // 16384*256
  float* HGAT  = Yb + 4194304;        // 16384*256
  float* GATWT = HGAT + 4194304;      // 256*256
  float* FSRC  = GATWT + 65536;       // 32*4*512
  float* FDST  = FSRC + 65536;        // 32*4*512
  float* POOL  = FDST + 65536;        // 32*256
  float* HIDb  = POOL + 8192;         // 32*128

  // 1. xp0 = x @ W_ih0^T + b_ih0
  gemm_bt<<<dim3(6, 128), 256, 0, stream>>>(x, Wih0, bih0, XPA, 16384, 768, 128);
  // 2. GRU layer 0
  gru_layer<<<32, 512, 0, stream>>>(XPA, Whh0, bhh0, G0);
  // 3. xp1 = g0 @ W_ih1^T + b_ih1
  gemm_bt<<<dim3(6, 128), 256, 0, stream>>>(G0, Wih1, bih1, XPA, 16384, 768, 256);
  // 4. GRU layer 1
  gru_layer<<<32, 512, 0, stream>>>(XPA, Whh1, bhh1, G1);
  // 5. GAT weight transpose + per-head features + attention
  gat_wt<<<256, 256, 0, stream>>>(gatW, GATWT);
  gemm_bt<<<dim3(2, 128), 256, 0, stream>>>(G1, GATWT, nullptr, HGAT, 16384, 256, 256);
  gat_fsd<<<dim3(32, 4), 512, 0, stream>>>(HGAT, gatA, FSRC, FDST);
  gat_attn<<<dim3(16, 4, 32), 256, 0, stream>>>(HGAT, FSRC, FDST, G0);
  // 6. y = LN(g + gat_out)
  ln_res<<<4096, 256, 0, stream>>>(G1, G0, lng, lnb, Yb);
  // 7. MHA
  gemm_bt<<<dim3(6, 128), 256, 0, stream>>>(Yb, inw, inb, XPA, 16384, 768, 256);
  mha_attn<<<dim3(16, 4, 32), 256, 0, stream>>>(XPA, HGAT);
  gemm_bt<<<dim3(2, 128), 256, 0, stream>>>(HGAT, outw, outb, Yb, 16384, 256, 256);
  // 8. pool + FC head
  mean_pool<<<32, 256, 0, stream>>>(Yb, POOL);
  fc1_k<<<32, 128, 0, stream>>>(POOL, f1w, f1b, HIDb);
  fc2_k<<<1, 256, 0, stream>>>(HIDb, f2w, f2b, out);
}